// Round 8
// baseline (166.621 us; speedup 1.0000x reference)
//
#include <hip/hip_runtime.h>
#include <hip/hip_bf16.h>

typedef __bf16 bf16_t;
typedef __bf16 bf16x8 __attribute__((ext_vector_type(8)));
typedef float f32x4 __attribute__((ext_vector_type(4)));

// async global->LDS, 16B per lane, dest = wave-uniform base + lane*16
#define GLL16(gp, lp)                                                          \
    __builtin_amdgcn_global_load_lds(                                          \
        (const __attribute__((address_space(1))) void*)(gp),                   \
        (__attribute__((address_space(3))) void*)(lp), 16, 0, 0)

#define SBAR() __builtin_amdgcn_s_barrier()
#define SCHED0() __builtin_amdgcn_sched_barrier(0)
#define WAIT_VM16() asm volatile("s_waitcnt vmcnt(16)" ::: "memory")
#define WAIT_VM4() asm volatile("s_waitcnt vmcnt(4)" ::: "memory")
#define WAIT_VM0() asm volatile("s_waitcnt vmcnt(0)" ::: "memory")
#define WAIT_LGKM0() asm volatile("s_waitcnt lgkmcnt(0)" ::: "memory")
#define MFMA_(d, a, b)                                                         \
    d = __builtin_amdgcn_mfma_f32_16x16x32_bf16(a, b, d, 0, 0, 0)

// ---------------- E8 lattice quantization (fp64 decisions) ----------------

__device__ __forceinline__ void nearest_D8_d(const double x[8], double f[8]) {
    double d[8];
    double fs = 0.0;
#pragma unroll
    for (int i = 0; i < 8; ++i) {
        f[i] = rint(x[i]);              // round-half-to-even == jnp.round
        d[i] = x[i] - f[i];
        fs += f[i];
    }
    long long s = (long long)fs;
    if (s & 1LL) {
        int idx = 0;
        double best = fabs(d[0]);
#pragma unroll
        for (int i = 1; i < 8; ++i) {
            double a = fabs(d[i]);
            if (a > best) { best = a; idx = i; }   // strict > : first max
        }
        f[idx] += (d[idx] >= 0.0) ? 1.0 : -1.0;
    }
}

__device__ __forceinline__ void e8_quantize_d(const double x[8], float q[8]) {
    double y0[8], y1[8], xs[8];
    nearest_D8_d(x, y0);
#pragma unroll
    for (int i = 0; i < 8; ++i) xs[i] = x[i] - 0.5;
    nearest_D8_d(xs, y1);
#pragma unroll
    for (int i = 0; i < 8; ++i) y1[i] += 0.5;
    double d0 = 0.0, d1 = 0.0;
#pragma unroll
    for (int i = 0; i < 8; ++i) {
        double a = x[i] - y0[i]; d0 += a * a;
        double b = x[i] - y1[i]; d1 += b * b;
    }
    bool take0 = (d0 <= d1);
#pragma unroll
    for (int i = 0; i < 8; ++i) q[i] = (float)(take0 ? y0[i] : y1[i]);
}

// one block per weight row: fp64 row norm -> E8 quantize -> bf16 Q + f32 scale
__global__ __launch_bounds__(256) void quant_kernel(
    const float* __restrict__ W, bf16_t* __restrict__ Q,
    float* __restrict__ scale, int IN, double sfd)
{
    const int row  = blockIdx.x;
    const int t    = threadIdx.x;
    const int lane = t & 63, w = t >> 6;
    const float* wrow = W + (size_t)row * IN;

    double ss = 0.0;
    for (int i = t; i < (IN >> 2); i += 256) {
        float4 v = *(const float4*)(wrow + i * 4);
        double a = v.x, b = v.y, c = v.z, d = v.w;
        ss += a * a + b * b + c * c + d * d;
    }
#pragma unroll
    for (int m = 1; m < 64; m <<= 1) ss += __shfl_xor(ss, m);
    __shared__ double red[4];
    if (lane == 0) red[w] = ss;
    __syncthreads();
    double S   = (red[0] + red[1]) + (red[2] + red[3]);
    double nsd = fmax(sqrt(S), 1e-8);

    for (int b = t; b < (IN >> 3); b += 256) {
        const float* xp = wrow + b * 8;
        float4 v0 = *(const float4*)xp;
        float4 v1 = *(const float4*)(xp + 4);
        double xd[8] = {v0.x, v0.y, v0.z, v0.w, v1.x, v1.y, v1.z, v1.w};
        double xsd[8];
#pragma unroll
        for (int i = 0; i < 8; ++i) xsd[i] = (xd[i] / nsd) * sfd;
        float qf[8];
        e8_quantize_d(xsd, qf);
        bf16x8 o;
#pragma unroll
        for (int i = 0; i < 8; ++i) o[i] = (bf16_t)qf[i];
        *(bf16x8*)(Q + (size_t)row * IN + b * 8) = o;
    }
    if (t == 0) scale[row] = (float)(nsd / sfd);
}

// ---------------- GEMM: 256x256 tile, BK=64, 8 waves, R4 3-window skeleton.
// A-operand fused-converted from f32 X: per K-tile, W1 issues 8 float4 loads
// (2-window latency cover), W3 cvt+ds_write after vmcnt(4). B staged via
// global_load_lds as before. Eliminates the separate x->bf16 pass.
// C[m,n] = (sum_k X[m,k]*B[n,k]) * scale[n] + bias[n]

#define BM 256
#define BN 256
#define BK 64

__global__ __launch_bounds__(512, 2) void gemm_kernel(
    const float* __restrict__ X,       // [M][K] f32
    const bf16_t* __restrict__ B,      // [N][K] bf16
    const float* __restrict__ scale,   // [N]
    const float* __restrict__ bias,    // [N]
    float* __restrict__ C,             // [M][N]
    int M, int N, int K)
{
    // [buf][A=0/B=1][half][128 rows * 64 cols]  = 128 KiB
    __shared__ __align__(16) bf16_t lds[2][2][2][8192];

    const int t    = threadIdx.x;
    const int lane = t & 63;
    const int w    = t >> 6;          // 0..7
    const int wr   = w >> 2;          // 0..1  (M rows of waves)
    const int wc   = w & 3;           // 0..3  (N cols of waves)

    // XCD-aware bijective block swizzle (m204)
    const int nwg = gridDim.x;
    const int bid = blockIdx.x;
    const int q8 = nwg >> 3, r8 = nwg & 7;
    const int xcd = bid & 7, idx = bid >> 3;
    const int swz = (xcd < r8 ? xcd * (q8 + 1) : r8 * (q8 + 1) + (xcd - r8) * q8) + idx;
    const int nbx = N / BN;
    const int bx = swz % nbx, by = swz / nbx;

    // staging source addressing (pre-swizzled k-slot so LDS dest is linear)
    const int rowq  = t >> 3;                          // 0..63
    const int kslot = ((t & 7) ^ (rowq & 7)) << 3;     // xor'd 8-elem slot
    const float*  gX = X + (size_t)(by * BM + rowq) * K + kslot;
    const bf16_t* gB = B + (size_t)(bx * BN + rowq) * K + kslot;

    // B staging: global_load_lds (linear dest)
#define STAGEB(bufi, h, kt)                                                    \
    do {                                                                       \
        const bf16_t* s_ = gB + (size_t)(h) * 128 * (size_t)K                  \
                              + (size_t)(kt) * BK;                             \
        GLL16(s_,                   &lds[bufi][1][h][t * 8]);                  \
        GLL16(s_ + 64 * (size_t)K,  &lds[bufi][1][h][t * 8 + 4096]);           \
    } while (0)

    // A staging: issue 8 float4 loads of f32 X for tile kt (both halves)
#define A_LOAD(FV, kt)                                                         \
    do {                                                                       \
        const float* p_ = gX + (size_t)(kt) * BK;                              \
        FV[0] = *(const f32x4*)(p_);                                           \
        FV[1] = *(const f32x4*)(p_ + 4);                                       \
        FV[2] = *(const f32x4*)(p_ + 64 * (size_t)K);                          \
        FV[3] = *(const f32x4*)(p_ + 64 * (size_t)K + 4);                      \
        FV[4] = *(const f32x4*)(p_ + 128 * (size_t)K);                         \
        FV[5] = *(const f32x4*)(p_ + 128 * (size_t)K + 4);                     \
        FV[6] = *(const f32x4*)(p_ + 192 * (size_t)K);                         \
        FV[7] = *(const f32x4*)(p_ + 192 * (size_t)K + 4);                     \
    } while (0)

    // A write: cvt 8 f32x4 -> 4 bf16x8, ds_write into linear-swizzled dest
#define A_WRITE(FV, bufi)                                                      \
    do {                                                                       \
        _Pragma("unroll")                                                      \
        for (int h_ = 0; h_ < 2; ++h_) {                                       \
            _Pragma("unroll")                                                  \
            for (int q_ = 0; q_ < 2; ++q_) {                                   \
                f32x4 lo_ = FV[h_ * 4 + q_ * 2];                               \
                f32x4 hi_ = FV[h_ * 4 + q_ * 2 + 1];                           \
                bf16x8 v_;                                                     \
                v_[0] = (bf16_t)lo_[0]; v_[1] = (bf16_t)lo_[1];                \
                v_[2] = (bf16_t)lo_[2]; v_[3] = (bf16_t)lo_[3];                \
                v_[4] = (bf16_t)hi_[0]; v_[5] = (bf16_t)hi_[1];                \
                v_[6] = (bf16_t)hi_[2]; v_[7] = (bf16_t)hi_[3];                \
                *(bf16x8*)(&lds[bufi][0][h_][t * 8 + q_ * 4096]) = v_;         \
            }                                                                  \
        }                                                                      \
    } while (0)

    // ds_read addressing: frag row r = R*16 + (lane&15); k-slot (s*4+lane>>4)
    // XOR'd with (r&7) == (lane&7). aoff folds (lane&15)*64 + swizzled slot*8.
    const int l15  = lane & 15;
    const int koff = lane >> 4;                        // 0..3
    const int aoff0 = l15 * 64 + (((koff)     ^ (lane & 7)) << 3);
    const int aoff1 = l15 * 64 + (((4 + koff) ^ (lane & 7)) << 3);

    f32x4 acc[8][4];
    const f32x4 zero = {0.f, 0.f, 0.f, 0.f};
#pragma unroll
    for (int R = 0; R < 8; ++R)
#pragma unroll
        for (int Cf = 0; Cf < 4; ++Cf) acc[R][Cf] = zero;

    const int NT = K / BK;             // 64 here

    f32x4 fst[8];                      // in-flight A staging regs (32 VGPR)

    // prologue: A0 loads, B0 GLL, A1 loads, B1 GLL; write A0, A1
    {
        f32x4 f0[8], f1[8];
        A_LOAD(f0, 0);
        STAGEB(0, 0, 0); STAGEB(0, 1, 0);
        A_LOAD(f1, 1);
        STAGEB(1, 0, 1); STAGEB(1, 1, 1);
        WAIT_VM16();                   // A0 arrived (leaves B0,A1,B1)
        A_WRITE(f0, 0);
        WAIT_VM4();                    // A1 arrived (leaves B1)
        A_WRITE(f1, 1);
        WAIT_LGKM0();
        SBAR();
        SCHED0();
    }

    bf16x8 af[4][2], b01[2][2], b23[2][2];

    for (int kt = 0; kt < NT; ++kt) {
        const int cur = kt & 1;
        const bf16_t* ldsA = &lds[cur][0][wr][0];
        const bf16_t* ldsB = &lds[cur][1][wc >> 1][(wc & 1) * 4096];
        const bool s2 = (kt + 2 < NT);

        // ==== W1: issue A(kt+2) f32 loads; 16 ds_reads; MFMA Q1+Q2 ====
        if (s2) A_LOAD(fst, kt + 2);
#pragma unroll
        for (int R = 0; R < 4; ++R) {
            af[R][0] = *(const bf16x8*)(ldsA + R * 1024 + aoff0);
            af[R][1] = *(const bf16x8*)(ldsA + R * 1024 + aoff1);
        }
#pragma unroll
        for (int c = 0; c < 2; ++c) {
            b01[c][0] = *(const bf16x8*)(ldsB + c * 1024 + aoff0);
            b01[c][1] = *(const bf16x8*)(ldsB + c * 1024 + aoff1);
        }
#pragma unroll
        for (int c = 0; c < 2; ++c) {
            b23[c][0] = *(const bf16x8*)(ldsB + (2 + c) * 1024 + aoff0);
            b23[c][1] = *(const bf16x8*)(ldsB + (2 + c) * 1024 + aoff1);
        }
        __builtin_amdgcn_s_setprio(1);
#pragma unroll
        for (int s = 0; s < 2; ++s)
#pragma unroll
            for (int R = 0; R < 4; ++R) {
                MFMA_(acc[R][0], af[R][s], b01[0][s]);
                MFMA_(acc[R][1], af[R][s], b01[1][s]);
            }
#pragma unroll
        for (int s = 0; s < 2; ++s)
#pragma unroll
            for (int R = 0; R < 4; ++R) {
                MFMA_(acc[R][2], af[R][s], b23[0][s]);
                MFMA_(acc[R][3], af[R][s], b23[1][s]);
            }
        __builtin_amdgcn_s_setprio(0);
        SBAR();            // all waves' B-reads + A r0-3 reads of tile kt done
        SCHED0();

        // ==== W2: 8 ds_reads (A r4-7); stage B(kt+2) GLL; MFMA Q3 ====
#pragma unroll
        for (int R = 0; R < 4; ++R) {
            af[R][0] = *(const bf16x8*)(ldsA + (4 + R) * 1024 + aoff0);
            af[R][1] = *(const bf16x8*)(ldsA + (4 + R) * 1024 + aoff1);
        }
        if (s2) { STAGEB(cur, 0, kt + 2); STAGEB(cur, 1, kt + 2); }
        __builtin_amdgcn_s_setprio(1);
#pragma unroll
        for (int s = 0; s < 2; ++s)
#pragma unroll
            for (int R = 0; R < 4; ++R) {
                MFMA_(acc[4 + R][2], af[R][s], b23[0][s]);
                MFMA_(acc[4 + R][3], af[R][s], b23[1][s]);
            }
        __builtin_amdgcn_s_setprio(0);
        SBAR();            // all waves' A-reads of tile kt complete
        SCHED0();

        // ==== W3: MFMA Q4; vmcnt -> A(kt+2) regs ready; cvt+write A ====
        __builtin_amdgcn_s_setprio(1);
#pragma unroll
        for (int s = 0; s < 2; ++s)
#pragma unroll
            for (int R = 0; R < 4; ++R) {
                MFMA_(acc[4 + R][0], af[R][s], b01[0][s]);
                MFMA_(acc[4 + R][1], af[R][s], b01[1][s]);
            }
        __builtin_amdgcn_s_setprio(0);
        if (kt < NT - 2) { WAIT_VM4(); }       // drains B(kt+1)GLL + A(kt+2)f32
        else if (kt == NT - 2) { WAIT_VM0(); }
        if (s2) A_WRITE(fst, cur);             // A(kt+2) -> buf[cur]
        WAIT_LGKM0();                          // publish ds_writes
        SBAR();            // tile kt+1 fully resident for all waves
        SCHED0();
    }

    // epilogue: D[row=(lane>>4)*4+j, col=lane&15] per 16x16 fragment
    const int r0 = by * BM + wr * 128 + (lane >> 4) * 4;
    const int c0 = bx * BN + wc * 64 + l15;
#pragma unroll
    for (int Cf = 0; Cf < 4; ++Cf) {
        const int col = c0 + Cf * 16;
        const float sc = scale[col];
        const float bi = bias[col];
#pragma unroll
        for (int R = 0; R < 8; ++R) {
            const int row = r0 + R * 16;
#pragma unroll
            for (int j = 0; j < 4; ++j)
                C[(size_t)(row + j) * N + col] = acc[R][Cf][j] * sc + bi;
        }
    }
#undef STAGEB
#undef A_LOAD
#undef A_WRITE
}

// ---------------- launch ----------------

extern "C" void kernel_launch(void* const* d_in, const int* in_sizes, int n_in,
                              void* d_out, int out_size, void* d_ws, size_t ws_size,
                              hipStream_t stream)
{
    const float* x    = (const float*)d_in[0];
    const float* wgt  = (const float*)d_in[1];
    const float* bias = (const float*)d_in[2];

    const int OUT = in_sizes[2];
    const int IN  = (int)((long long)in_sizes[1] / OUT);
    const int M   = (int)((long long)in_sizes[0] / IN);
    const int N = OUT, K = IN;

    double ad = (double)OUT / 10000.0;
    if (ad < 0.5) ad = 0.5;
    if (ad > 2.0) ad = 2.0;
    const double sfd = 60.0 * ad;      // = 30.0 for OUT=4096

    bf16_t* Q  = (bf16_t*)d_ws;
    float*  sc = (float*)((char*)d_ws + (size_t)OUT * IN * sizeof(bf16_t));
    float*  C  = (float*)d_out;

    quant_kernel<<<OUT, 256, 0, stream>>>(wgt, Q, sc, IN, sfd);

    int grid = (M / BM) * (N / BN);
    gemm_kernel<<<grid, 512, 0, stream>>>(x, Q, sc, bias, C, M, N, K);
}

// Round 9
// 158.416 us; speedup vs baseline: 1.0518x; 1.0518x over previous
//
#include <hip/hip_runtime.h>
#include <hip/hip_bf16.h>

typedef __bf16 bf16_t;
typedef __bf16 bf16x8 __attribute__((ext_vector_type(8)));
typedef float f32x4 __attribute__((ext_vector_type(4)));

// async global->LDS, 16B per lane, dest = wave-uniform base + lane*16
#define GLL16(gp, lp)                                                          \
    __builtin_amdgcn_global_load_lds(                                          \
        (const __attribute__((address_space(1))) void*)(gp),                   \
        (__attribute__((address_space(3))) void*)(lp), 16, 0, 0)

#define SBAR() __builtin_amdgcn_s_barrier()
#define SCHED0() __builtin_amdgcn_sched_barrier(0)
#define WAIT_VM4() asm volatile("s_waitcnt vmcnt(4)" ::: "memory")
#define WAIT_VM0() asm volatile("s_waitcnt vmcnt(0)" ::: "memory")
#define WAIT_LGKM8() asm volatile("s_waitcnt lgkmcnt(8)" ::: "memory")
#define WAIT_LGKM0() asm volatile("s_waitcnt lgkmcnt(0)" ::: "memory")
#define MFMA_(d, a, b)                                                         \
    d = __builtin_amdgcn_mfma_f32_16x16x32_bf16(a, b, d, 0, 0, 0)

// ---------------- E8 lattice quantization (fp64 decisions) ----------------

__device__ __forceinline__ void nearest_D8_d(const double x[8], double f[8]) {
    double d[8];
    double fs = 0.0;
#pragma unroll
    for (int i = 0; i < 8; ++i) {
        f[i] = rint(x[i]);              // round-half-to-even == jnp.round
        d[i] = x[i] - f[i];
        fs += f[i];
    }
    long long s = (long long)fs;
    if (s & 1LL) {
        int idx = 0;
        double best = fabs(d[0]);
#pragma unroll
        for (int i = 1; i < 8; ++i) {
            double a = fabs(d[i]);
            if (a > best) { best = a; idx = i; }   // strict > : first max
        }
        f[idx] += (d[idx] >= 0.0) ? 1.0 : -1.0;
    }
}

__device__ __forceinline__ void e8_quantize_d(const double x[8], float q[8]) {
    double y0[8], y1[8], xs[8];
    nearest_D8_d(x, y0);
#pragma unroll
    for (int i = 0; i < 8; ++i) xs[i] = x[i] - 0.5;
    nearest_D8_d(xs, y1);
#pragma unroll
    for (int i = 0; i < 8; ++i) y1[i] += 0.5;
    double d0 = 0.0, d1 = 0.0;
#pragma unroll
    for (int i = 0; i < 8; ++i) {
        double a = x[i] - y0[i]; d0 += a * a;
        double b = x[i] - y1[i]; d1 += b * b;
    }
    bool take0 = (d0 <= d1);
#pragma unroll
    for (int i = 0; i < 8; ++i) q[i] = (float)(take0 ? y0[i] : y1[i]);
}

// fused: blocks [0,OUT) quantize weight rows; blocks [OUT, OUT+CB) cvt x->bf16
__global__ __launch_bounds__(256) void prep_kernel(
    const float* __restrict__ W, bf16_t* __restrict__ Q,
    float* __restrict__ scale, int IN, double sfd,
    const float* __restrict__ x, bf16_t* __restrict__ Xb, long long n8,
    int OUT, int CB)
{
    if (blockIdx.x >= (unsigned)OUT) {
        // ---- cvt part ----
        long long i = (long long)(blockIdx.x - OUT) * 256 + threadIdx.x;
        long long stride = (long long)CB * 256;
        for (; i < n8; i += stride) {
            float4 v0 = *(const float4*)(x + i * 8);
            float4 v1 = *(const float4*)(x + i * 8 + 4);
            bf16x8 o;
            o[0] = (bf16_t)v0.x; o[1] = (bf16_t)v0.y;
            o[2] = (bf16_t)v0.z; o[3] = (bf16_t)v0.w;
            o[4] = (bf16_t)v1.x; o[5] = (bf16_t)v1.y;
            o[6] = (bf16_t)v1.z; o[7] = (bf16_t)v1.w;
            *(bf16x8*)(Xb + i * 8) = o;
        }
        return;
    }
    // ---- quant part ----
    const int row  = blockIdx.x;
    const int t    = threadIdx.x;
    const int lane = t & 63, w = t >> 6;
    const float* wrow = W + (size_t)row * IN;

    double ss = 0.0;
    for (int i = t; i < (IN >> 2); i += 256) {
        float4 v = *(const float4*)(wrow + i * 4);
        double a = v.x, b = v.y, c = v.z, d = v.w;
        ss += a * a + b * b + c * c + d * d;
    }
#pragma unroll
    for (int m = 1; m < 64; m <<= 1) ss += __shfl_xor(ss, m);
    __shared__ double red[4];
    if (lane == 0) red[w] = ss;
    __syncthreads();
    double S   = (red[0] + red[1]) + (red[2] + red[3]);
    double nsd = fmax(sqrt(S), 1e-8);

    for (int b = t; b < (IN >> 3); b += 256) {
        const float* xp = wrow + b * 8;
        float4 v0 = *(const float4*)xp;
        float4 v1 = *(const float4*)(xp + 4);
        double xd[8] = {v0.x, v0.y, v0.z, v0.w, v1.x, v1.y, v1.z, v1.w};
        double xsd[8];
#pragma unroll
        for (int i = 0; i < 8; ++i) xsd[i] = (xd[i] / nsd) * sfd;
        float qf[8];
        e8_quantize_d(xsd, qf);
        bf16x8 o;
#pragma unroll
        for (int i = 0; i < 8; ++i) o[i] = (bf16_t)qf[i];
        *(bf16x8*)(Q + (size_t)row * IN + b * 8) = o;
    }
    if (t == 0) scale[row] = (float)(nsd / sfd);
}

// ---------------- GEMM: 256x256 tile, BK=64, 8 waves, m201-style 8-phase.
// 2 K-tiles per iteration (static buffer indices). 2 GLL per phase, mapping
// derived from region lifetimes: P1/P2 stage A(O)->buf1, P3/P4 B(E+2)->buf0,
// P5/P6 A(E+2)->buf0, P7/P8 B(O+2)->buf1. Counted vmcnt(4) at P4 (tile O
// resident) and P8 (tile E+2 resident) ONLY - never 0 in main loop.
// Per phase: {ds_reads; 2xGLL; [lgkm8]; BAR; lgkm0; prio1; 16 MFMA; prio0; BAR}
// C[m,n] = (sum_k A[m,k]*B[n,k]) * scale[n] + bias[n]

#define BM 256
#define BN 256
#define BK 64

__global__ __launch_bounds__(512, 2) void gemm_kernel(
    const bf16_t* __restrict__ A,      // [M][K]
    const bf16_t* __restrict__ B,      // [N][K]
    const float* __restrict__ scale,   // [N]
    const float* __restrict__ bias,    // [N]
    float* __restrict__ C,             // [M][N]
    int M, int N, int K)
{
    // [buf][A=0/B=1][half][128 rows * 64 cols]  = 128 KiB
    __shared__ __align__(16) bf16_t lds[2][2][2][8192];

    const int t    = threadIdx.x;
    const int lane = t & 63;
    const int w    = t >> 6;          // 0..7
    const int wr   = w >> 2;          // 0..1  (M rows of waves)
    const int wc   = w & 3;           // 0..3  (N cols of waves)

    // XCD-aware bijective block swizzle (m204)
    const int nwg = gridDim.x;
    const int bid = blockIdx.x;
    const int q8 = nwg >> 3, r8 = nwg & 7;
    const int xcd = bid & 7, idx = bid >> 3;
    const int swz = (xcd < r8 ? xcd * (q8 + 1) : r8 * (q8 + 1) + (xcd - r8) * q8) + idx;
    const int nbx = N / BN;
    const int bx = swz % nbx, by = swz / nbx;

    // staging source addressing (pre-swizzled k-slot so LDS dest is linear)
    const int rowq  = t >> 3;                          // 0..63
    const int kslot = ((t & 7) ^ (rowq & 7)) << 3;     // xor'd 8-elem slot
    const bf16_t* gA = A + (size_t)(by * BM + rowq) * K + kslot;
    const bf16_t* gB = B + (size_t)(bx * BN + rowq) * K + kslot;

#define STAGE(isB, bufi, h, kt)                                                \
    do {                                                                       \
        const bf16_t* s_ = ((isB) ? gB : gA)                                   \
            + (size_t)(h) * 128 * (size_t)K + (size_t)(kt) * BK;               \
        GLL16(s_,                   &lds[bufi][isB][h][t * 8]);                \
        GLL16(s_ + 64 * (size_t)K,  &lds[bufi][isB][h][t * 8 + 4096]);         \
    } while (0)

    // ds_read addressing: frag row r = R*16 + (lane&15); k-slot (s*4+lane>>4)
    // XOR'd with (r&7) == (lane&7). aoff folds (lane&15)*64 + swizzled slot*8.
    const int l15  = lane & 15;
    const int koff = lane >> 4;                        // 0..3
    const int aoff0 = l15 * 64 + (((koff)     ^ (lane & 7)) << 3);
    const int aoff1 = l15 * 64 + (((4 + koff) ^ (lane & 7)) << 3);

    f32x4 acc[8][4];
    const f32x4 zero = {0.f, 0.f, 0.f, 0.f};
#pragma unroll
    for (int R = 0; R < 8; ++R)
#pragma unroll
        for (int Cf = 0; Cf < 4; ++Cf) acc[R][Cf] = zero;

    const int NT = K / BK;             // even, >= 4
    const int NI = NT / 2;

    // read-base pointers (static per buffer)
    const bf16_t* A0p = &lds[0][0][wr][0];
    const bf16_t* B0p = &lds[0][1][wc >> 1][(wc & 1) * 4096];
    const bf16_t* A1p = &lds[1][0][wr][0];
    const bf16_t* B1p = &lds[1][1][wc >> 1][(wc & 1) * 4096];

    bf16x8 af[4][2], b01[2][2], b23[2][2];

    // phase building blocks
#define RD_A03(AP)                                                             \
    _Pragma("unroll")                                                          \
    for (int R = 0; R < 4; ++R) {                                              \
        af[R][0] = *(const bf16x8*)((AP) + R * 1024 + aoff0);                  \
        af[R][1] = *(const bf16x8*)((AP) + R * 1024 + aoff1);                  \
    }
#define RD_A47(AP)                                                             \
    _Pragma("unroll")                                                          \
    for (int R = 0; R < 4; ++R) {                                              \
        af[R][0] = *(const bf16x8*)((AP) + (4 + R) * 1024 + aoff0);            \
        af[R][1] = *(const bf16x8*)((AP) + (4 + R) * 1024 + aoff1);            \
    }
#define RD_B01(BP)                                                             \
    _Pragma("unroll")                                                          \
    for (int c = 0; c < 2; ++c) {                                              \
        b01[c][0] = *(const bf16x8*)((BP) + c * 1024 + aoff0);                 \
        b01[c][1] = *(const bf16x8*)((BP) + c * 1024 + aoff1);                 \
    }
#define RD_B23(BP)                                                             \
    _Pragma("unroll")                                                          \
    for (int c = 0; c < 2; ++c) {                                              \
        b23[c][0] = *(const bf16x8*)((BP) + (2 + c) * 1024 + aoff0);           \
        b23[c][1] = *(const bf16x8*)((BP) + (2 + c) * 1024 + aoff1);           \
    }
#define PH_MID() do { SBAR(); WAIT_LGKM0(); SCHED0();                          \
                      __builtin_amdgcn_s_setprio(1); } while (0)
#define PH_END() do { __builtin_amdgcn_s_setprio(0); SBAR(); } while (0)
#define MM_Q(RB, CB, AF, BF)                                                   \
    _Pragma("unroll")                                                          \
    for (int s = 0; s < 2; ++s)                                                \
        _Pragma("unroll")                                                      \
        for (int R = 0; R < 4; ++R) {                                          \
            MFMA_(acc[(RB) + R][(CB)],     AF[R][s], BF[0][s]);                \
            MFMA_(acc[(RB) + R][(CB) + 1], AF[R][s], BF[1][s]);                \
        }

    // prologue: tile0 A+B (8 GLL), tile1 B (4 GLL); vmcnt(4) -> tile0 resident
    STAGE(0, 0, 0, 0); STAGE(0, 0, 1, 0);
    STAGE(1, 0, 0, 0); STAGE(1, 0, 1, 0);
    STAGE(1, 1, 0, 1); STAGE(1, 1, 1, 1);
    WAIT_VM4();
    SBAR();
    SCHED0();

    for (int i = 0; i < NI - 1; ++i) {
        const int E = 2 * i;
        // ---- P1: rd A0-3,B01(buf0); stage A(O)h0->buf1 ----
        RD_A03(A0p); RD_B01(B0p);
        STAGE(0, 1, 0, E + 1);
        WAIT_LGKM8();
        PH_MID(); MM_Q(0, 0, af, b01); PH_END();
        // ---- P2: rd B23(buf0); stage A(O)h1->buf1 ----
        RD_B23(B0p);
        STAGE(0, 1, 1, E + 1);
        PH_MID(); MM_Q(0, 2, af, b23); PH_END();
        // ---- P3: rd A4-7(buf0); stage B(E+2)h0->buf0 ----
        RD_A47(A0p);
        STAGE(1, 0, 0, E + 2);
        PH_MID(); MM_Q(4, 2, af, b23); PH_END();
        // ---- P4: stage B(E+2)h1->buf0; vmcnt(4) [tile O resident] ----
        STAGE(1, 0, 1, E + 2);
        WAIT_VM4();
        PH_MID(); MM_Q(4, 0, af, b01); PH_END();
        // ---- P5: rd A0-3,B01(buf1); stage A(E+2)h0->buf0 ----
        RD_A03(A1p); RD_B01(B1p);
        STAGE(0, 0, 0, E + 2);
        WAIT_LGKM8();
        PH_MID(); MM_Q(0, 0, af, b01); PH_END();
        // ---- P6: rd B23(buf1); stage A(E+2)h1->buf0 ----
        RD_B23(B1p);
        STAGE(0, 0, 1, E + 2);
        PH_MID(); MM_Q(0, 2, af, b23); PH_END();
        // ---- P7: rd A4-7(buf1); stage B(O+2)h0->buf1 ----
        RD_A47(A1p);
        STAGE(1, 1, 0, E + 3);
        PH_MID(); MM_Q(4, 2, af, b23); PH_END();
        // ---- P8: stage B(O+2)h1->buf1; vmcnt(4) [tile E+2 resident] ----
        STAGE(1, 1, 1, E + 3);
        WAIT_VM4();
        PH_MID(); MM_Q(4, 0, af, b01); PH_END();
    }

    // tail iteration (tiles NT-2, NT-1): no restaging
    {
        // P1
        RD_A03(A0p); RD_B01(B0p);
        STAGE(0, 1, 0, NT - 1);
        WAIT_LGKM8();
        PH_MID(); MM_Q(0, 0, af, b01); PH_END();
        // P2
        RD_B23(B0p);
        STAGE(0, 1, 1, NT - 1);
        PH_MID(); MM_Q(0, 2, af, b23); PH_END();
        // P3
        RD_A47(A0p);
        PH_MID(); MM_Q(4, 2, af, b23); PH_END();
        // P4: drain all (tile NT-1 resident)
        WAIT_VM0();
        PH_MID(); MM_Q(4, 0, af, b01); PH_END();
        // P5
        RD_A03(A1p); RD_B01(B1p);
        WAIT_LGKM8();
        PH_MID(); MM_Q(0, 0, af, b01); PH_END();
        // P6
        RD_B23(B1p);
        PH_MID(); MM_Q(0, 2, af, b23); PH_END();
        // P7
        RD_A47(A1p);
        PH_MID(); MM_Q(4, 2, af, b23); PH_END();
        // P8
        PH_MID(); MM_Q(4, 0, af, b01); PH_END();
    }

    // epilogue: D[row=(lane>>4)*4+j, col=lane&15] per 16x16 fragment
    const int r0 = by * BM + wr * 128 + (lane >> 4) * 4;
    const int c0 = bx * BN + wc * 64 + l15;
#pragma unroll
    for (int Cf = 0; Cf < 4; ++Cf) {
        const int col = c0 + Cf * 16;
        const float sc = scale[col];
        const float bi = bias[col];
#pragma unroll
        for (int R = 0; R < 8; ++R) {
            const int row = r0 + R * 16;
#pragma unroll
            for (int j = 0; j < 4; ++j)
                C[(size_t)(row + j) * N + col] = acc[R][Cf][j] * sc + bi;
        }
    }
#undef STAGE
#undef RD_A03
#undef RD_A47
#undef RD_B01
#undef RD_B23
#undef PH_MID
#undef PH_END
#undef MM_Q
}

// ---------------- launch ----------------

extern "C" void kernel_launch(void* const* d_in, const int* in_sizes, int n_in,
                              void* d_out, int out_size, void* d_ws, size_t ws_size,
                              hipStream_t stream)
{
    const float* x    = (const float*)d_in[0];
    const float* wgt  = (const float*)d_in[1];
    const float* bias = (const float*)d_in[2];

    const int OUT = in_sizes[2];
    const int IN  = (int)((long long)in_sizes[1] / OUT);
    const int M   = (int)((long long)in_sizes[0] / IN);
    const int N = OUT, K = IN;

    double ad = (double)OUT / 10000.0;
    if (ad < 0.5) ad = 0.5;
    if (ad > 2.0) ad = 2.0;
    const double sfd = 60.0 * ad;      // = 30.0 for OUT=4096

    bf16_t* Q  = (bf16_t*)d_ws;
    bf16_t* Xb = (bf16_t*)((char*)d_ws + (size_t)OUT * IN * sizeof(bf16_t));
    float*  sc = (float*)((char*)d_ws + (size_t)OUT * IN * sizeof(bf16_t)
                                      + (size_t)M * IN * sizeof(bf16_t));
    float*  C  = (float*)d_out;

    long long n8 = (long long)M * IN / 8;
    const int CB = 2048;
    prep_kernel<<<OUT + CB, 256, 0, stream>>>(wgt, Q, sc, IN, sfd,
                                              x, Xb, n8, OUT, CB);

    int grid = (M / BM) * (N / BN);
    gemm_kernel<<<grid, 512, 0, stream>>>(Xb, Q, sc, bias, C, M, N, K);
}

// Round 10
// 158.405 us; speedup vs baseline: 1.0519x; 1.0001x over previous
//
#include <hip/hip_runtime.h>
#include <hip/hip_bf16.h>

typedef __bf16 bf16_t;
typedef __bf16 bf16x8 __attribute__((ext_vector_type(8)));
typedef float f32x4 __attribute__((ext_vector_type(4)));

// async global->LDS, 16B per lane, dest = wave-uniform base + lane*16
#define GLL16(gp, lp)                                                          \
    __builtin_amdgcn_global_load_lds(                                          \
        (const __attribute__((address_space(1))) void*)(gp),                   \
        (__attribute__((address_space(3))) void*)(lp), 16, 0, 0)

#define SBAR() __builtin_amdgcn_s_barrier()
#define SCHED0() __builtin_amdgcn_sched_barrier(0)
#define WAIT_VM4() asm volatile("s_waitcnt vmcnt(4)" ::: "memory")
#define WAIT_VM0() asm volatile("s_waitcnt vmcnt(0)" ::: "memory")
#define WAIT_LGKM8() asm volatile("s_waitcnt lgkmcnt(8)" ::: "memory")
#define WAIT_LGKM0() asm volatile("s_waitcnt lgkmcnt(0)" ::: "memory")
#define MFMA_(d, a, b)                                                         \
    d = __builtin_amdgcn_mfma_f32_16x16x32_bf16(a, b, d, 0, 0, 0)

// ---------------- E8 lattice quantization (fp64 decisions) ----------------

__device__ __forceinline__ void nearest_D8_d(const double x[8], double f[8]) {
    double d[8];
    double fs = 0.0;
#pragma unroll
    for (int i = 0; i < 8; ++i) {
        f[i] = rint(x[i]);              // round-half-to-even == jnp.round
        d[i] = x[i] - f[i];
        fs += f[i];
    }
    long long s = (long long)fs;
    if (s & 1LL) {
        int idx = 0;
        double best = fabs(d[0]);
#pragma unroll
        for (int i = 1; i < 8; ++i) {
            double a = fabs(d[i]);
            if (a > best) { best = a; idx = i; }   // strict > : first max
        }
        f[idx] += (d[idx] >= 0.0) ? 1.0 : -1.0;
    }
}

__device__ __forceinline__ void e8_quantize_d(const double x[8], float q[8]) {
    double y0[8], y1[8], xs[8];
    nearest_D8_d(x, y0);
#pragma unroll
    for (int i = 0; i < 8; ++i) xs[i] = x[i] - 0.5;
    nearest_D8_d(xs, y1);
#pragma unroll
    for (int i = 0; i < 8; ++i) y1[i] += 0.5;
    double d0 = 0.0, d1 = 0.0;
#pragma unroll
    for (int i = 0; i < 8; ++i) {
        double a = x[i] - y0[i]; d0 += a * a;
        double b = x[i] - y1[i]; d1 += b * b;
    }
    bool take0 = (d0 <= d1);
#pragma unroll
    for (int i = 0; i < 8; ++i) q[i] = (float)(take0 ? y0[i] : y1[i]);
}

// fused: blocks [0,OUT) quantize weight rows; blocks [OUT, OUT+CB) cvt x->bf16
__global__ __launch_bounds__(256) void prep_kernel(
    const float* __restrict__ W, bf16_t* __restrict__ Q,
    float* __restrict__ scale, int IN, double sfd,
    const float* __restrict__ x, bf16_t* __restrict__ Xb, long long n8,
    int OUT, int CB)
{
    if (blockIdx.x >= (unsigned)OUT) {
        // ---- cvt part ----
        long long i = (long long)(blockIdx.x - OUT) * 256 + threadIdx.x;
        long long stride = (long long)CB * 256;
        for (; i < n8; i += stride) {
            float4 v0 = *(const float4*)(x + i * 8);
            float4 v1 = *(const float4*)(x + i * 8 + 4);
            bf16x8 o;
            o[0] = (bf16_t)v0.x; o[1] = (bf16_t)v0.y;
            o[2] = (bf16_t)v0.z; o[3] = (bf16_t)v0.w;
            o[4] = (bf16_t)v1.x; o[5] = (bf16_t)v1.y;
            o[6] = (bf16_t)v1.z; o[7] = (bf16_t)v1.w;
            *(bf16x8*)(Xb + i * 8) = o;
        }
        return;
    }
    // ---- quant part ----
    const int row  = blockIdx.x;
    const int t    = threadIdx.x;
    const int lane = t & 63, w = t >> 6;
    const float* wrow = W + (size_t)row * IN;

    double ss = 0.0;
    for (int i = t; i < (IN >> 2); i += 256) {
        float4 v = *(const float4*)(wrow + i * 4);
        double a = v.x, b = v.y, c = v.z, d = v.w;
        ss += a * a + b * b + c * c + d * d;
    }
#pragma unroll
    for (int m = 1; m < 64; m <<= 1) ss += __shfl_xor(ss, m);
    __shared__ double red[4];
    if (lane == 0) red[w] = ss;
    __syncthreads();
    double S   = (red[0] + red[1]) + (red[2] + red[3]);
    double nsd = fmax(sqrt(S), 1e-8);

    for (int b = t; b < (IN >> 3); b += 256) {
        const float* xp = wrow + b * 8;
        float4 v0 = *(const float4*)xp;
        float4 v1 = *(const float4*)(xp + 4);
        double xd[8] = {v0.x, v0.y, v0.z, v0.w, v1.x, v1.y, v1.z, v1.w};
        double xsd[8];
#pragma unroll
        for (int i = 0; i < 8; ++i) xsd[i] = (xd[i] / nsd) * sfd;
        float qf[8];
        e8_quantize_d(xsd, qf);
        bf16x8 o;
#pragma unroll
        for (int i = 0; i < 8; ++i) o[i] = (bf16_t)qf[i];
        *(bf16x8*)(Q + (size_t)row * IN + b * 8) = o;
    }
    if (t == 0) scale[row] = (float)(nsd / sfd);
}

// ---------------- GEMM: 256x256 tile, BK=64, 8 waves, m201-style 8-phase.
// 2 K-tiles per iteration (static buffer indices). 2 GLL per phase, mapping
// derived from region lifetimes: P1/P2 stage A(O)->buf1, P3/P4 B(E+2)->buf0,
// P5/P6 A(E+2)->buf0, P7/P8 B(O+2)->buf1. Counted vmcnt(4) at P4 (tile O
// resident) and P8 (tile E+2 resident) ONLY - never 0 in main loop.
// Per phase: {ds_reads; 2xGLL; [lgkm8]; BAR; lgkm0; prio1; 16 MFMA; prio0; BAR}
// C[m,n] = (sum_k A[m,k]*B[n,k]) * scale[n] + bias[n]
//
// Session verdict (R2-R9): five schedule structures converge to 125-141us
// (MfmaUtil 41-48%, bank conflicts 0, no spills). Occupancy is pinned at
// 2 waves/SIMD by acc[8][4]=128 VGPR; all tile splits raise LDS traffic.
// Locking in the best verified variant.

#define BM 256
#define BN 256
#define BK 64

__global__ __launch_bounds__(512, 2) void gemm_kernel(
    const bf16_t* __restrict__ A,      // [M][K]
    const bf16_t* __restrict__ B,      // [N][K]
    const float* __restrict__ scale,   // [N]
    const float* __restrict__ bias,    // [N]
    float* __restrict__ C,             // [M][N]
    int M, int N, int K)
{
    // [buf][A=0/B=1][half][128 rows * 64 cols]  = 128 KiB
    __shared__ __align__(16) bf16_t lds[2][2][2][8192];

    const int t    = threadIdx.x;
    const int lane = t & 63;
    const int w    = t >> 6;          // 0..7
    const int wr   = w >> 2;          // 0..1  (M rows of waves)
    const int wc   = w & 3;           // 0..3  (N cols of waves)

    // XCD-aware bijective block swizzle (m204)
    const int nwg = gridDim.x;
    const int bid = blockIdx.x;
    const int q8 = nwg >> 3, r8 = nwg & 7;
    const int xcd = bid & 7, idx = bid >> 3;
    const int swz = (xcd < r8 ? xcd * (q8 + 1) : r8 * (q8 + 1) + (xcd - r8) * q8) + idx;
    const int nbx = N / BN;
    const int bx = swz % nbx, by = swz / nbx;

    // staging source addressing (pre-swizzled k-slot so LDS dest is linear)
    const int rowq  = t >> 3;                          // 0..63
    const int kslot = ((t & 7) ^ (rowq & 7)) << 3;     // xor'd 8-elem slot
    const bf16_t* gA = A + (size_t)(by * BM + rowq) * K + kslot;
    const bf16_t* gB = B + (size_t)(bx * BN + rowq) * K + kslot;

#define STAGE(isB, bufi, h, kt)                                                \
    do {                                                                       \
        const bf16_t* s_ = ((isB) ? gB : gA)                                   \
            + (size_t)(h) * 128 * (size_t)K + (size_t)(kt) * BK;               \
        GLL16(s_,                   &lds[bufi][isB][h][t * 8]);                \
        GLL16(s_ + 64 * (size_t)K,  &lds[bufi][isB][h][t * 8 + 4096]);         \
    } while (0)

    // ds_read addressing: frag row r = R*16 + (lane&15); k-slot (s*4+lane>>4)
    // XOR'd with (r&7) == (lane&7). aoff folds (lane&15)*64 + swizzled slot*8.
    const int l15  = lane & 15;
    const int koff = lane >> 4;                        // 0..3
    const int aoff0 = l15 * 64 + (((koff)     ^ (lane & 7)) << 3);
    const int aoff1 = l15 * 64 + (((4 + koff) ^ (lane & 7)) << 3);

    f32x4 acc[8][4];
    const f32x4 zero = {0.f, 0.f, 0.f, 0.f};
#pragma unroll
    for (int R = 0; R < 8; ++R)
#pragma unroll
        for (int Cf = 0; Cf < 4; ++Cf) acc[R][Cf] = zero;

    const int NT = K / BK;             // even, >= 4
    const int NI = NT / 2;

    // read-base pointers (static per buffer)
    const bf16_t* A0p = &lds[0][0][wr][0];
    const bf16_t* B0p = &lds[0][1][wc >> 1][(wc & 1) * 4096];
    const bf16_t* A1p = &lds[1][0][wr][0];
    const bf16_t* B1p = &lds[1][1][wc >> 1][(wc & 1) * 4096];

    bf16x8 af[4][2], b01[2][2], b23[2][2];

    // phase building blocks
#define RD_A03(AP)                                                             \
    _Pragma("unroll")                                                          \
    for (int R = 0; R < 4; ++R) {                                              \
        af[R][0] = *(const bf16x8*)((AP) + R * 1024 + aoff0);                  \
        af[R][1] = *(const bf16x8*)((AP) + R * 1024 + aoff1);                  \
    }
#define RD_A47(AP)                                                             \
    _Pragma("unroll")                                                          \
    for (int R = 0; R < 4; ++R) {                                              \
        af[R][0] = *(const bf16x8*)((AP) + (4 + R) * 1024 + aoff0);            \
        af[R][1] = *(const bf16x8*)((AP) + (4 + R) * 1024 + aoff1);            \
    }
#define RD_B01(BP)                                                             \
    _Pragma("unroll")                                                          \
    for (int c = 0; c < 2; ++c) {                                              \
        b01[c][0] = *(const bf16x8*)((BP) + c * 1024 + aoff0);                 \
        b01[c][1] = *(const bf16x8*)((BP) + c * 1024 + aoff1);                 \
    }
#define RD_B23(BP)                                                             \
    _Pragma("unroll")                                                          \
    for (int c = 0; c < 2; ++c) {                                              \
        b23[c][0] = *(const bf16x8*)((BP) + (2 + c) * 1024 + aoff0);           \
        b23[c][1] = *(const bf16x8*)((BP) + (2 + c) * 1024 + aoff1);           \
    }
#define PH_MID() do { SBAR(); WAIT_LGKM0(); SCHED0();                          \
                      __builtin_amdgcn_s_setprio(1); } while (0)
#define PH_END() do { __builtin_amdgcn_s_setprio(0); SBAR(); } while (0)
#define MM_Q(RB, CB, AF, BF)                                                   \
    _Pragma("unroll")                                                          \
    for (int s = 0; s < 2; ++s)                                                \
        _Pragma("unroll")                                                      \
        for (int R = 0; R < 4; ++R) {                                          \
            MFMA_(acc[(RB) + R][(CB)],     AF[R][s], BF[0][s]);                \
            MFMA_(acc[(RB) + R][(CB) + 1], AF[R][s], BF[1][s]);                \
        }

    // prologue: tile0 A+B (8 GLL), tile1 B (4 GLL); vmcnt(4) -> tile0 resident
    STAGE(0, 0, 0, 0); STAGE(0, 0, 1, 0);
    STAGE(1, 0, 0, 0); STAGE(1, 0, 1, 0);
    STAGE(1, 1, 0, 1); STAGE(1, 1, 1, 1);
    WAIT_VM4();
    SBAR();
    SCHED0();

    for (int i = 0; i < NI - 1; ++i) {
        const int E = 2 * i;
        // ---- P1: rd A0-3,B01(buf0); stage A(O)h0->buf1 ----
        RD_A03(A0p); RD_B01(B0p);
        STAGE(0, 1, 0, E + 1);
        WAIT_LGKM8();
        PH_MID(); MM_Q(0, 0, af, b01); PH_END();
        // ---- P2: rd B23(buf0); stage A(O)h1->buf1 ----
        RD_B23(B0p);
        STAGE(0, 1, 1, E + 1);
        PH_MID(); MM_Q(0, 2, af, b23); PH_END();
        // ---- P3: rd A4-7(buf0); stage B(E+2)h0->buf0 ----
        RD_A47(A0p);
        STAGE(1, 0, 0, E + 2);
        PH_MID(); MM_Q(4, 2, af, b23); PH_END();
        // ---- P4: stage B(E+2)h1->buf0; vmcnt(4) [tile O resident] ----
        STAGE(1, 0, 1, E + 2);
        WAIT_VM4();
        PH_MID(); MM_Q(4, 0, af, b01); PH_END();
        // ---- P5: rd A0-3,B01(buf1); stage A(E+2)h0->buf0 ----
        RD_A03(A1p); RD_B01(B1p);
        STAGE(0, 0, 0, E + 2);
        WAIT_LGKM8();
        PH_MID(); MM_Q(0, 0, af, b01); PH_END();
        // ---- P6: rd B23(buf1); stage A(E+2)h1->buf0 ----
        RD_B23(B1p);
        STAGE(0, 0, 1, E + 2);
        PH_MID(); MM_Q(0, 2, af, b23); PH_END();
        // ---- P7: rd A4-7(buf1); stage B(O+2)h0->buf1 ----
        RD_A47(A1p);
        STAGE(1, 1, 0, E + 3);
        PH_MID(); MM_Q(4, 2, af, b23); PH_END();
        // ---- P8: stage B(O+2)h1->buf1; vmcnt(4) [tile E+2 resident] ----
        STAGE(1, 1, 1, E + 3);
        WAIT_VM4();
        PH_MID(); MM_Q(4, 0, af, b01); PH_END();
    }

    // tail iteration (tiles NT-2, NT-1): no restaging
    {
        // P1
        RD_A03(A0p); RD_B01(B0p);
        STAGE(0, 1, 0, NT - 1);
        WAIT_LGKM8();
        PH_MID(); MM_Q(0, 0, af, b01); PH_END();
        // P2
        RD_B23(B0p);
        STAGE(0, 1, 1, NT - 1);
        PH_MID(); MM_Q(0, 2, af, b23); PH_END();
        // P3
        RD_A47(A0p);
        PH_MID(); MM_Q(4, 2, af, b23); PH_END();
        // P4: drain all (tile NT-1 resident)
        WAIT_VM0();
        PH_MID(); MM_Q(4, 0, af, b01); PH_END();
        // P5
        RD_A03(A1p); RD_B01(B1p);
        WAIT_LGKM8();
        PH_MID(); MM_Q(0, 0, af, b01); PH_END();
        // P6
        RD_B23(B1p);
        PH_MID(); MM_Q(0, 2, af, b23); PH_END();
        // P7
        RD_A47(A1p);
        PH_MID(); MM_Q(4, 2, af, b23); PH_END();
        // P8
        PH_MID(); MM_Q(4, 0, af, b01); PH_END();
    }

    // epilogue: D[row=(lane>>4)*4+j, col=lane&15] per 16x16 fragment
    // (stores are full-cache-line coalesced: lanes 0-15 cover 64B of one row)
    const int r0 = by * BM + wr * 128 + (lane >> 4) * 4;
    const int c0 = bx * BN + wc * 64 + l15;
#pragma unroll
    for (int Cf = 0; Cf < 4; ++Cf) {
        const int col = c0 + Cf * 16;
        const float sc = scale[col];
        const float bi = bias[col];
#pragma unroll
        for (int R = 0; R < 8; ++R) {
            const int row = r0 + R * 16;
#pragma unroll
            for (int j = 0; j < 4; ++j)
                C[(size_t)(row + j) * N + col] = acc[R][Cf][j] * sc + bi;
        }
    }
#undef STAGE
#undef RD_A03
#undef RD_A47
#undef RD_B01
#undef RD_B23
#undef PH_MID
#undef PH_END
#undef MM_Q
}

// ---------------- launch ----------------

extern "C" void kernel_launch(void* const* d_in, const int* in_sizes, int n_in,
                              void* d_out, int out_size, void* d_ws, size_t ws_size,
                              hipStream_t stream)
{
    const float* x    = (const float*)d_in[0];
    const float* wgt  = (const float*)d_in[1];
    const float* bias = (const float*)d_in[2];

    const int OUT = in_sizes[2];
    const int IN  = (int)((long long)in_sizes[1] / OUT);
    const int M   = (int)((long long)in_sizes[0] / IN);
    const int N = OUT, K = IN;

    double ad = (double)OUT / 10000.0;
    if (ad < 0.5) ad = 0.5;
    if (ad > 2.0) ad = 2.0;
    const double sfd = 60.0 * ad;      // = 30.0 for OUT=4096

    bf16_t* Q  = (bf16_t*)d_ws;
    bf16_t* Xb = (bf16_t*)((char*)d_ws + (size_t)OUT * IN * sizeof(bf16_t));
    float*  sc = (float*)((char*)d_ws + (size_t)OUT * IN * sizeof(bf16_t)
                                      + (size_t)M * IN * sizeof(bf16_t));
    float*  C  = (float*)d_out;

    long long n8 = (long long)M * IN / 8;
    const int CB = 2048;
    prep_kernel<<<OUT + CB, 256, 0, stream>>>(wgt, Q, sc, IN, sfd,
                                              x, Xb, n8, OUT, CB);

    int grid = (M / BM) * (N / BN);
    gemm_kernel<<<grid, 512, 0, stream>>>(Xb, Q, sc, bias, C, M, N, K);
}